// Round 13
// baseline (259.917 us; speedup 1.0000x reference)
//
#include <hip/hip_runtime.h>
#include <hip/hip_fp16.h>
#include <math.h>

// LinearCaps2d, BATCH=256, N = B_TYPES*H*W = 2048, C=10, POSE=16, 3 routing iters.
// R13 = R12 compute (phase-B-free, packed-V) with 512-thread blocks:
//   8 waves = 4 b-tiles x 2 n-groups (wave owns 2 of the 4 staged n) -> 16 waves/CU (was 8),
//   traffic shape byte-identical to R12 (same grid, same staging, same atomic count).
//   End-of-pass: g0<->g1 exchange c-halves via LDS overlay, each flushes 5 c with the
//   verified transpose+full-line atomic pattern.
// ws: s0,s1,s2 [40960] f32.

typedef _Float16 f16;
typedef _Float16 f16x2 __attribute__((ext_vector_type(2)));
typedef _Float16 f16x4 __attribute__((ext_vector_type(4)));
typedef _Float16 f16x8 __attribute__((ext_vector_type(8)));
typedef __fp16   h16x2 __attribute__((ext_vector_type(2)));
typedef float f32x4 __attribute__((ext_vector_type(4)));

__device__ __forceinline__ f16x2 pk(float a, float b) {
    h16x2 t = __builtin_amdgcn_cvt_pkrtz(a, b);
    return __builtin_bit_cast(f16x2, t);
}

#if __has_builtin(__builtin_amdgcn_fdot2)
__device__ __forceinline__ float FDOT2(f16x2 a, f16x2 b, float c) {
    return __builtin_amdgcn_fdot2(__builtin_bit_cast(h16x2, a),
                                  __builtin_bit_cast(h16x2, b), c, false);
}
#else
__device__ __forceinline__ float FDOT2(f16x2 a, f16x2 b, float c) {
    return c + (float)a[0] * (float)b[0] + (float)a[1] * (float)b[1];
}
#endif

constexpr int WS_ROW = 28;   // f16 row stride (16 i + 12 pad) -- verified low-conflict
constexpr int XS_ROW = 76;   // f16 row stride (4n x 16 i + pad)

__device__ __forceinline__ float xorsum4(float v) {
    v += __shfl_xor(v, 16, 64);
    v += __shfl_xor(v, 32, 64);
    return v;
}

// packed f16x2 cross-quad reduction: one shfl pair for two c's (verified R11/R12)
__device__ __forceinline__ f16x2 xorsum4h(f16x2 v) {
    union { f16x2 h; int i; } u;
    union { int i; f16x2 h; } w;
    u.h = v; w.i = __shfl_xor(u.i, 16, 64); v = v + w.h;
    u.h = v; w.i = __shfl_xor(u.i, 32, 64); v = v + w.h;
    return v;
}

__device__ __forceinline__ f16x4 cvt4(float4 w) {
    f16x2 a = pk(w.x, w.y);
    f16x2 b = pk(w.z, w.w);
    f16x4 r; r[0] = a[0]; r[1] = a[1]; r[2] = b[0]; r[3] = b[1];
    return r;
}

// grid: 512 blocks = 128 n-groups (16 n) x 4 b-groups (64 b); 512 thr = 8 waves.
// wave = (t = b-tile 0..3, g = n-group 0..1); wave handles n_local = g*2+{0,1} per iter.
template<int PASS>
__global__ __launch_bounds__(512, 4)
void pass_k(const float* __restrict__ poses, const float* __restrict__ weight,
            const float* __restrict__ bias,
            const float* __restrict__ sp0, const float* __restrict__ sp1,
            float* __restrict__ s_dst)
{
    __shared__ __align__(16) char ldsbuf[45568];
    f16* Ws = (f16*)ldsbuf;                  // 640 rows x WS_ROW = 35840 B
    f16* xs = (f16*)(ldsbuf + 35840);        // 64 x XS_ROW = 9728 B
    // end-of-pass overlay (after compute): two 20480 B float regions
    float* trA = (float*)ldsbuf;             // g1's c0..4 partials -> read by g0
    float* trB = (float*)(ldsbuf + 20480);   // g0's c5..9 partials -> read by g1

    const int tid  = threadIdx.x;
    const int blk  = blockIdx.x;
    const int ngrp = blk >> 2;          // 128 n-groups (16 n each)
    const int b0   = (blk & 3) * 64;    // 4 b-groups
    const int wave = tid >> 6;
    const int lane = tid & 63;
    const int q    = lane >> 4;
    const int lo   = lane & 15;
    const int t    = wave & 3;          // b-tile
    const int g    = wave >> 2;         // n-group
    const int wtb  = t * 16;
    const int bg   = b0 + wtb;          // wave's global batch base

    // ---- inline squash: vsp[c] = v[b=bg+lo][c][o=q*4..q*4+3], packed f16
    f16x2 vsp[10][2];
    if (PASS >= 1) {
        const int rowb = (bg + lo) * 10;
        #pragma unroll
        for (int c = 0; c < 10; ++c) {
            float4 bb = *(const float4*)(bias + c * 16 + q * 4);
            float4 sa = *(const float4*)(sp0 + (size_t)(rowb + c) * 16 + q * 4);
            float t0 = sa.x + bb.x, t1 = sa.y + bb.y, t2 = sa.z + bb.z, t3 = sa.w + bb.w;
            float n2 = xorsum4(t0*t0 + t1*t1 + t2*t2 + t3*t3);
            float sc = n2 / (1.f + n2) * rsqrtf(n2 + 1e-8f);
            float v0 = sc*t0, v1 = sc*t1, v2 = sc*t2, v3 = sc*t3;
            if (PASS == 2) {
                float4 sb = *(const float4*)(sp1 + (size_t)(rowb + c) * 16 + q * 4);
                float u0 = sb.x + bb.x, u1 = sb.y + bb.y, u2 = sb.z + bb.z, u3 = sb.w + bb.w;
                float m2 = xorsum4(u0*u0 + u1*u1 + u2*u2 + u3*u3);
                float sc2 = m2 / (1.f + m2) * rsqrtf(m2 + 1e-8f);
                v0 += sc2*u0; v1 += sc2*u1; v2 += sc2*u2; v3 += sc2*u3;
            }
            vsp[c][0] = pk(v0, v1);
            vsp[c][1] = pk(v2, v3);
        }
    }

    // ---- staging (software-pipelined), same tile as R12, spread over 512 threads
    float4 wreg[5];
    float4 xreg[2];
    const int b_loc = tid >> 3, part = tid & 7;   // 64 b x 8 parts (8 floats each)

    auto load_iter = [&](int l) {
        const float* wp = weight + (size_t)(ngrp * 4 + l) * 10240;   // 4n x 160 x 16
        #pragma unroll
        for (int k = 0; k < 5; ++k) wreg[k] = ((const float4*)wp)[tid + k * 512];
        const float* xp = poses + (size_t)(b0 + b_loc) * 32768
                          + (size_t)(ngrp * 16 + l * 4) * 16 + part * 8;
        xreg[0] = ((const float4*)xp)[0];
        xreg[1] = ((const float4*)xp)[1];
    };
    auto store_iter = [&]() {
        #pragma unroll
        for (int k = 0; k < 5; ++k) {
            const int f = tid + k * 512;          // float4 index in [0,2560)
            *(f16x4*)&Ws[(f >> 2) * WS_ROW + (f & 3) * 4] = cvt4(wreg[k]);
        }
        f16x4 r0 = cvt4(xreg[0]), r1 = cvt4(xreg[1]);
        f16x8 r = __builtin_shufflevector(r0, r1, 0, 1, 2, 3, 4, 5, 6, 7);
        *(f16x8*)&xs[b_loc * XS_ROW + part * 8] = r;
    };

    f32x4 acc[10];
    #pragma unroll
    for (int c = 0; c < 10; ++c) acc[c] = (f32x4){0.f, 0.f, 0.f, 0.f};

    load_iter(0);

    for (int l = 0; l < 4; ++l) {
        __syncthreads();
        store_iter();
        if (l + 1 < 4) load_iter(l + 1);
        __syncthreads();

        #pragma unroll
        for (int j = 0; j < 2; ++j) {
            const int n = g * 2 + j;            // this wave's n within the staged 4
            f16x4 bx = *(const f16x4*)&xs[(wtb + lo) * XS_ROW + n * 16 + q * 4];
            f16x2 Vh[10][2];
            #pragma unroll
            for (int c = 0; c < 10; ++c) {
                f16x4 aw = *(const f16x4*)&Ws[((n * 10 + c) * 16 + lo) * WS_ROW + q * 4];
                f32x4 V = __builtin_amdgcn_mfma_f32_16x16x16f16(
                    aw, bx, (f32x4){0.f, 0.f, 0.f, 0.f}, 0, 0, 0);
                Vh[c][0] = pk(V[0], V[1]);
                Vh[c][1] = pk(V[2], V[3]);
            }

            float cfv[10];
            if (PASS >= 1) {
                float lg[10];
                #pragma unroll
                for (int cp = 0; cp < 5; ++cp) {
                    const int c0 = cp * 2, c1 = cp * 2 + 1;
                    float p0 = FDOT2(Vh[c0][0], vsp[c0][0], 0.f);
                    p0 = FDOT2(Vh[c0][1], vsp[c0][1], p0);
                    float p1 = FDOT2(Vh[c1][0], vsp[c1][0], 0.f);
                    p1 = FDOT2(Vh[c1][1], vsp[c1][1], p1);
                    f16x2 pr = xorsum4h(pk(p0, p1));
                    lg[c0] = (float)pr[0];
                    lg[c1] = (float)pr[1];
                }
                float m = lg[0];
                #pragma unroll
                for (int c = 1; c < 10; ++c) m = fmaxf(m, lg[c]);
                float sum = 0.f;
                #pragma unroll
                for (int c = 0; c < 10; ++c) { lg[c] = __expf(lg[c] - m); sum += lg[c]; }
                const float inv = 1.f / sum;
                #pragma unroll
                for (int c = 0; c < 10; ++c) cfv[c] = lg[c] * inv;
            }

            #pragma unroll
            for (int c = 0; c < 10; ++c) {
                const float w = (PASS == 0) ? 1.f : cfv[c];
                acc[c][0] = fmaf(w, (float)Vh[c][0][0], acc[c][0]);
                acc[c][1] = fmaf(w, (float)Vh[c][0][1], acc[c][1]);
                acc[c][2] = fmaf(w, (float)Vh[c][1][0], acc[c][2]);
                acc[c][3] = fmaf(w, (float)Vh[c][1][1], acc[c][3]);
            }
        }
    }

    // ---- combine n-group partials (g0<->g1 swap c-halves) + transpose + flush.
    __syncthreads();                         // all compute reads of Ws/xs done
    {
        // give away the half we don't flush: g0 gives c5..9 to trB, g1 gives c0..4 to trA
        float* tw = g ? trA : trB;
        const int cgive = g ? 0 : 5;
        #pragma unroll
        for (int cc = 0; cc < 5; ++cc) {
            const int idx = ((t * 5 + cc) * 16 + lo) * 4 + q;       // float4 index
            *(f32x4*)&tw[idx * 4] = acc[cgive + cc];
        }
    }
    __syncthreads();
    {
        float* td = g ? trB : trA;           // partner's partials for our kept half
        const int ckeep = g ? 5 : 0;
        f32x4 cmb[5];
        #pragma unroll
        for (int cc = 0; cc < 5; ++cc) {
            const int idx = ((t * 5 + cc) * 16 + lo) * 4 + q;
            f32x4 p = *(const f32x4*)&td[idx * 4];
            cmb[cc] = acc[ckeep + cc] + p;
        }
        // per-wave transpose scratch = our own just-read subregion (wave-synchronous reuse)
        float* scr = td + t * 1280;
        const float fs = (PASS == 0) ? 0.1f : 1.f;
        #pragma unroll
        for (int cc = 0; cc < 5; ++cc) {
            *(f32x4*)&scr[lo * 20 + q * 4] = cmb[cc];
            float r0 = scr[(q * 4 + 0) * 20 + lo];
            float r1 = scr[(q * 4 + 1) * 20 + lo];
            float r2 = scr[(q * 4 + 2) * 20 + lo];
            float r3 = scr[(q * 4 + 3) * 20 + lo];
            float* sp = s_dst + ((size_t)(bg + q * 4) * 10 + ckeep + cc) * 16 + lo;
            unsafeAtomicAdd(sp + 0 * 160, fs * r0);
            unsafeAtomicAdd(sp + 1 * 160, fs * r1);
            unsafeAtomicAdd(sp + 2 * 160, fs * r2);
            unsafeAtomicAdd(sp + 3 * 160, fs * r3);
        }
    }
}

// final squash: 2560 rows, one (b,c) per thread (verified R3/R7).
__global__ __launch_bounds__(256)
void epi_k(const float* __restrict__ s2, const float* __restrict__ bias,
           float* __restrict__ out)
{
    const int t = blockIdx.x * 256 + threadIdx.x;
    if (t >= 2560) return;
    const int c = t % 10;
    const float* sp = s2 + (size_t)t * 16;
    const float* bp = bias + c * 16;
    float sv[16];
    float n2 = 0.f;
    #pragma unroll
    for (int o = 0; o < 16; ++o) { float v = sp[o] + bp[o]; sv[o] = v; n2 += v * v; }
    const float scale = n2 / (1.f + n2) * rsqrtf(n2 + 1e-8f);
    float a2 = 0.f;
    #pragma unroll
    for (int o = 0; o < 16; ++o) {
        float v = scale * sv[o];
        out[(size_t)t * 16 + o] = v;
        a2 += v * v;
    }
    out[40960 + t] = sqrtf(a2 + 1e-8f);
}

extern "C" void kernel_launch(void* const* d_in, const int* in_sizes, int n_in,
                              void* d_out, int out_size, void* d_ws, size_t ws_size,
                              hipStream_t stream)
{
    const float* poses  = (const float*)d_in[0];
    // d_in[1] (input_caps_activations) unused by the reference.
    const float* weight = (const float*)d_in[2];
    const float* bias   = (const float*)d_in[3];
    float* out = (float*)d_out;
    float* s0 = (float*)d_ws;
    float* s1 = s0 + 40960;
    float* s2 = s1 + 40960;

    (void)hipMemsetAsync(d_ws, 0, 3 * 40960 * sizeof(float), stream);

    pass_k<0><<<512, 512, 0, stream>>>(poses, weight, bias, nullptr, nullptr, s0);
    pass_k<1><<<512, 512, 0, stream>>>(poses, weight, bias, s0, nullptr, s1);
    pass_k<2><<<512, 512, 0, stream>>>(poses, weight, bias, s0, s1, s2);
    epi_k<<<10, 256, 0, stream>>>(s2, bias, out);
}